// Round 4
// baseline (26.214 us; speedup 1.0000x reference)
//
#include <hip/hip_runtime.h>

#define MARGIN 0.5f
#define EPS    1e-6f
#define BN     8192
#define NPDB   512
#define TPB    256
#define G      32               // blocks; each owns NPDB/G = 16 groups
#define GPB    (NPDB / G)       // 16 (ownership test uses >>4)
#define CAP    1024             // owned-elements buffer (mean 256, huge margin)
#define FIXSCALE 4294967296.0   // 2^32 fixed point -> order-independent sum

__global__ __launch_bounds__(TPB) void pairloss_part(
    const float* __restrict__ preds,
    const float* __restrict__ targets,
    const int*   __restrict__ pdb,
    unsigned long long* __restrict__ ws,   // [0]=fixed sum [1]=count [2]=arrival
    float* __restrict__ out)
{
    __shared__ int hist[GPB], scanex[GPB], cur[GPB];
    __shared__ float2 sorted[CAP];
    __shared__ unsigned char grp[CAP];
    __shared__ double rsum[TPB / 64];
    __shared__ int    rcnt[TPB / 64];

    const int t    = threadIdx.x;
    const int b    = blockIdx.x;
    const int lane = t & 63;
    const int wv   = t >> 6;

    if (t < GPB) hist[t] = 0;
    __syncthreads();

    const int4* pdb4 = (const int4*)pdb;

    // ---- pass 1: histogram of OWNED groups (scan all ids, coalesced int4) ----
    #pragma unroll
    for (int k = 0; k < BN / 4 / TPB; ++k) {          // 8 iterations
        const int4 g4 = pdb4[t + k * TPB];
        if ((g4.x >> 4) == b) atomicAdd(&hist[g4.x & (GPB - 1)], 1);
        if ((g4.y >> 4) == b) atomicAdd(&hist[g4.y & (GPB - 1)], 1);
        if ((g4.z >> 4) == b) atomicAdd(&hist[g4.z & (GPB - 1)], 1);
        if ((g4.w >> 4) == b) atomicAdd(&hist[g4.w & (GPB - 1)], 1);
    }
    __syncthreads();

    // ---- scan 16 bins (lanes 0..15 of wave 0) ----
    if (t < GPB) {
        int v = hist[t];
        #pragma unroll
        for (int off = 1; off < GPB; off <<= 1) {
            const int n = __shfl_up(v, off);
            if (lane >= off) v += n;
        }
        scanex[t] = v - hist[t];
        cur[t]    = v - hist[t];
    }
    __syncthreads();

    // ---- pass 2: scatter owned elements into group-contiguous LDS ----
    #pragma unroll
    for (int k = 0; k < BN / 4 / TPB; ++k) {
        const int idx = t + k * TPB;
        const int4 g4 = pdb4[idx];
        const int i0  = idx * 4;
        const int gs[4] = { g4.x, g4.y, g4.z, g4.w };
        #pragma unroll
        for (int c = 0; c < 4; ++c) {
            if ((gs[c] >> 4) == b) {
                const int lg  = gs[c] & (GPB - 1);
                const int pos = atomicAdd(&cur[lg], 1);
                if (pos < CAP) {
                    sorted[pos] = make_float2(preds[i0 + c], targets[i0 + c]);
                    grp[pos]    = (unsigned char)lg;
                }
            }
        }
    }
    __syncthreads();

    const int tot = scanex[GPB - 1] + hist[GPB - 1];

    // ---- sweep: each owned element vs its own group ----
    float sum = 0.0f;
    int   cnt = 0;
    for (int s = t; s < tot; s += TPB) {
        const float2 pt = sorted[s];
        const int g  = grp[s];
        const int st = scanex[g];
        const int en = st + hist[g];
        const float base = MARGIN - pt.x;
        const float ti   = pt.y;
        for (int j = st; j < en; ++j) {    // j==s can't pass (ti > ti+eps false)
            const float2 q = sorted[j];
            const bool ok = ti > (q.y + EPS);
            sum += ok ? fmaxf(base + q.x, 0.0f) : 0.0f;
            cnt += ok ? 1 : 0;
        }
    }

    // ---- block reduce ----
    double ds = (double)sum;
    #pragma unroll
    for (int off = 32; off > 0; off >>= 1) {
        ds  += __shfl_down(ds, off);
        cnt += __shfl_down(cnt, off);
    }
    if (lane == 0) { rsum[wv] = ds; rcnt[wv] = cnt; }
    __syncthreads();

    if (t == 0) {
        double S = 0.0; int C = 0;
        #pragma unroll
        for (int w = 0; w < TPB / 64; ++w) { S += rsum[w]; C += rcnt[w]; }
        atomicAdd(&ws[0], (unsigned long long)(long long)(S * FIXSCALE));
        atomicAdd(&ws[1], (unsigned long long)(unsigned int)C);
        __threadfence();
        const unsigned int old = atomicAdd((unsigned int*)&ws[2], 1u);
        if (old == G - 1) {                 // last block finalizes
            __threadfence();
            const unsigned long long fs = atomicAdd(&ws[0], 0ull);
            const unsigned long long fc = atomicAdd(&ws[1], 0ull);
            const double S2 = (double)(long long)fs / FIXSCALE;
            const long long C2 = (long long)fc;
            out[0] = (C2 == 0) ? 0.0f : (float)(S2 / (double)C2);
        }
    }
}

extern "C" void kernel_launch(void* const* d_in, const int* in_sizes, int n_in,
                              void* d_out, int out_size, void* d_ws, size_t ws_size,
                              hipStream_t stream)
{
    const float* preds   = (const float*)d_in[0];
    const float* targets = (const float*)d_in[1];
    const int*   pdb     = (const int*)d_in[2];
    float* out = (float*)d_out;
    unsigned long long* ws = (unsigned long long*)d_ws;

    hipMemsetAsync(ws, 0, 3 * sizeof(unsigned long long), stream);
    pairloss_part<<<G, TPB, 0, stream>>>(preds, targets, pdb, ws, out);
}